// Round 5
// baseline (402.003 us; speedup 1.0000x reference)
//
#include <hip/hip_runtime.h>
#include <hip/hip_bf16.h>
#include <hip/hip_fp16.h>
#include <cstdint>
#include <cstddef>

// Problem constants (fixed by reference setup_inputs)
#define EMBED  256
#define NV_PER_B 13294
#define M_REAL  26588
#define M_PAD   26624          // 208 * 128
#define NQPB   8               // queries per msda block

// Spatial pyramid (structural constants from reference SHAPES)
__constant__ const int c_H[4]  = {100, 50, 25, 13};
__constant__ const int c_W[4]  = {100, 50, 25, 13};
__constant__ const int c_ST[4] = {0, 10000, 12500, 13125};

typedef __attribute__((ext_vector_type(8))) short bf16x8;
typedef __attribute__((ext_vector_type(4))) float f32x4;

__device__ inline short f2bf(float x) {
    __hip_bfloat16 h = __float2bfloat16(x);
    return *reinterpret_cast<short*>(&h);
}

// ---------------- tiny weight convert: fp32 -> bf16 + concat ----------------
__global__ __launch_bounds__(256) void wconv_kernel(
    const float* __restrict__ wv, const float* __restrict__ wsamp,
    const float* __restrict__ wattn, const float* __restrict__ wo,
    const float* __restrict__ bsamp, const float* __restrict__ battn,
    short* __restrict__ wv_bf, short* __restrict__ wcat_bf,
    short* __restrict__ wo_bf, float* __restrict__ bias_cat)
{
    const int i = blockIdx.x * 256 + threadIdx.x;
    if (i < 16384) {  // W_val, W_out: 65536/4 float4s each
        float4 a = ((const float4*)wv)[i];
        float4 c = ((const float4*)wo)[i];
        ((short4*)wv_bf)[i] = make_short4(f2bf(a.x), f2bf(a.y), f2bf(a.z), f2bf(a.w));
        ((short4*)wo_bf)[i] = make_short4(f2bf(c.x), f2bf(c.y), f2bf(c.z), f2bf(c.w));
    }
    if (i < 24576) {  // W_cat = [W_samp(256x256); W_attn(128x256)]
        float4 a = (i < 16384) ? ((const float4*)wsamp)[i]
                               : ((const float4*)wattn)[i - 16384];
        ((short4*)wcat_bf)[i] = make_short4(f2bf(a.x), f2bf(a.y), f2bf(a.z), f2bf(a.w));
    }
    if (i < 96) {     // bias_cat = [b_samp(256); b_attn(128)]
        float4 a = (i < 64) ? ((const float4*)bsamp)[i]
                            : ((const float4*)battn)[i - 64];
        ((float4*)bias_cat)[i] = a;
    }
}

// ---------------- proj GEMM: fp32 A read + in-register bf16 cvt ----------------
// 128x128 tile, K=256, 8 K-iters double-buffered. A: buffer->VGPR->cvt->ds_write
// (same XOR-swizzled [row][4 slots of 16B] layout); B: global_load_lds bf16.
// grid.y: 0,1 -> vproj(256 cols); 2,3 -> qo samp cols; 4 -> qo attn cols.
__global__ __launch_bounds__(256) void proj_gemm_kernel(
    const float* __restrict__ value, const short* __restrict__ wv_bf,
    const float* __restrict__ b_val, __half* __restrict__ vproj,
    const float* __restrict__ query, const short* __restrict__ wcat_bf,
    const float* __restrict__ bias_cat, __half* __restrict__ qo, int M)
{
    constexpr int K = 256;
    __shared__ __align__(16) char smem[36864];   // 2 stages x (A 8KB + B 8KB); epilogue reuse

    const int t = threadIdx.x;
    const int wave = t >> 6, lane = t & 63;
    const int lr16 = lane & 15, qk = lane >> 4;
    const int wrow = wave & 1, wcol = wave >> 1;
    const int y = blockIdx.y;
    const int bm = blockIdx.x * 128;

    const float* A; const short* Wt; const float* bias; __half* Cc; int Nst, bn;
    if (y < 2) { A = value; Wt = wv_bf;   bias = b_val;    Cc = vproj; Nst = 256; bn = y * 128; }
    else       { A = query; Wt = wcat_bf; bias = bias_cat; Cc = qo;    Nst = 384; bn = (y - 2) * 128; }

    // A staging coords: thread t -> row = t>>1 (0..127), khalf = (t&1)*16
    const int arow = t >> 1;
    const int akh  = (t & 1) * 16;
    const size_t abase = (size_t)min(bm + arow, M - 1) * K + akh;
    // A LDS slots: global k-blocks kbg = akh/8 + {0,1}; slot = kbg ^ (arow&3)
    const int aslot0 = ((t & 1) * 2 + 0) ^ (arow & 3);
    const int aslot1 = ((t & 1) * 2 + 1) ^ (arow & 3);

    // B staging coords (global_load_lds, as round 4)
    const int brow0 = t >> 2, brow1 = brow0 + 64;
    const int kbl  = t & 3;
    const int kbg0 = kbl ^ (brow0 & 3);
    const int kbg1 = kbl ^ (brow1 & 3);
    const size_t b0 = (size_t)(bn + brow0) * K + kbg0 * 8;
    const size_t b1 = (size_t)(bn + brow1) * K + kbg1 * 8;
    const int swz  = (qk ^ (lr16 & 3)) * 16;

    f32x4 acc[4][4] = {};
    float4 areg[4];

    auto loadA = [&](int k0) {
        #pragma unroll
        for (int i = 0; i < 4; ++i)
            areg[i] = *(const float4*)&A[abase + k0 + i * 4];
    };
    auto issueB = [&](int stage, int k0) {
        char* sb = smem + stage * 16384 + 8192 + wave * 1024;  // wave-uniform base
        __builtin_amdgcn_global_load_lds(
            (const __attribute__((address_space(1))) void*)(Wt + b0 + k0),
            (__attribute__((address_space(3))) void*)(sb), 16, 0, 0);
        __builtin_amdgcn_global_load_lds(
            (const __attribute__((address_space(1))) void*)(Wt + b1 + k0),
            (__attribute__((address_space(3))) void*)(sb + 4096), 16, 0, 0);
    };
    auto writeA = [&](int stage) {
        char* sa = smem + stage * 16384;
        __align__(16) short h8a[8], h8b[8];
        const float* f = (const float*)areg;
        #pragma unroll
        for (int i = 0; i < 8; ++i) { h8a[i] = f2bf(f[i]); h8b[i] = f2bf(f[8 + i]); }
        *(bf16x8*)(sa + arow * 64 + aslot0 * 16) = *(const bf16x8*)h8a;
        *(bf16x8*)(sa + arow * 64 + aslot1 * 16) = *(const bf16x8*)h8b;
    };

    loadA(0);
    issueB(0, 0);
    writeA(0);
    #pragma unroll
    for (int it = 0; it < 8; ++it) {
        __syncthreads();   // stage it&1 resident (A ds_writes ordered; B vmcnt drained)
        if (it + 1 < 8) {
            loadA((it + 1) * 32);
            issueB((it + 1) & 1, (it + 1) * 32);
        }
        const char* sa = smem + (it & 1) * 16384;
        const char* sb = sa + 8192;
        bf16x8 af[4], bfr[4];
        #pragma unroll
        for (int mi = 0; mi < 4; ++mi) {
            const int m = wrow * 64 + mi * 16 + lr16;
            af[mi] = *(const bf16x8*)(sa + m * 64 + ((qk ^ (m & 3)) * 16));
        }
        #pragma unroll
        for (int ni = 0; ni < 4; ++ni) {
            const int n = wcol * 64 + ni * 16 + lr16;
            bfr[ni] = *(const bf16x8*)(sb + n * 64 + ((qk ^ (n & 3)) * 16));
        }
        #pragma unroll
        for (int mi = 0; mi < 4; ++mi)
            #pragma unroll
            for (int ni = 0; ni < 4; ++ni)
                acc[mi][ni] = __builtin_amdgcn_mfma_f32_16x16x32_bf16(
                    af[mi], bfr[ni], acc[mi][ni], 0, 0, 0);
        if (it + 1 < 8) writeA((it + 1) & 1);
    }

    // epilogue: per-wave LDS transpose (64x64 fp16, stride 72 halves) -> dwordx4 stores
    __syncthreads();
    __half* ep = (__half*)(smem + wave * 9216);
    const int colbase = bn + wcol * 64;
    float bv[4];
    #pragma unroll
    for (int ni = 0; ni < 4; ++ni) bv[ni] = bias[colbase + ni * 16 + lr16];
    #pragma unroll
    for (int mi = 0; mi < 4; ++mi)
        #pragma unroll
        for (int ni = 0; ni < 4; ++ni)
            #pragma unroll
            for (int r = 0; r < 4; ++r)
                ep[(mi * 16 + qk * 4 + r) * 72 + ni * 16 + lr16] =
                    __float2half(acc[mi][ni][r] + bv[ni]);
    __syncthreads();
    const int er = lane >> 3, ec = (lane & 7) * 8;
    #pragma unroll
    for (int pass = 0; pass < 8; ++pass) {
        const int r = pass * 8 + er;
        const int4 vv = *(const int4*)&ep[r * 72 + ec];
        const int grow = bm + wrow * 64 + r;
        *(int4*)&Cc[(size_t)grow * Nst + colbase + ec] = vv;
    }
}

// ---------------- final GEMM: core(bf16) @ W_out^T + b_out -> fp32 d_out ----------------
__device__ __forceinline__ void gemm_kloop_bf16(
    const short* __restrict__ A, const short* __restrict__ Wt,
    int bm, int bn, char* smem, f32x4 (&acc)[4][4],
    int t, int wave, int lane)
{
    constexpr int K = 256;
    const int row0 = t >> 2, row1 = row0 + 64;
    const int kbl  = t & 3;
    const int kbg0 = kbl ^ (row0 & 3);
    const int kbg1 = kbl ^ (row1 & 3);
    const size_t a0 = (size_t)(bm + row0) * K + kbg0 * 8;
    const size_t a1 = (size_t)(bm + row1) * K + kbg1 * 8;
    const size_t b0 = (size_t)(bn + row0) * K + kbg0 * 8;
    const size_t b1 = (size_t)(bn + row1) * K + kbg1 * 8;
    const int lr16 = lane & 15, qk = lane >> 4;
    const int wrow = wave & 1, wcol = wave >> 1;

    auto issue = [&](int stage, int k0) {
        char* sa = smem + stage * 16384 + wave * 1024;
        char* sb = sa + 8192;
        __builtin_amdgcn_global_load_lds(
            (const __attribute__((address_space(1))) void*)(A + a0 + k0),
            (__attribute__((address_space(3))) void*)(sa), 16, 0, 0);
        __builtin_amdgcn_global_load_lds(
            (const __attribute__((address_space(1))) void*)(A + a1 + k0),
            (__attribute__((address_space(3))) void*)(sa + 4096), 16, 0, 0);
        __builtin_amdgcn_global_load_lds(
            (const __attribute__((address_space(1))) void*)(Wt + b0 + k0),
            (__attribute__((address_space(3))) void*)(sb), 16, 0, 0);
        __builtin_amdgcn_global_load_lds(
            (const __attribute__((address_space(1))) void*)(Wt + b1 + k0),
            (__attribute__((address_space(3))) void*)(sb + 4096), 16, 0, 0);
    };

    issue(0, 0);
    #pragma unroll
    for (int it = 0; it < 8; ++it) {
        __syncthreads();
        if (it + 1 < 8) issue((it + 1) & 1, (it + 1) * 32);
        const char* sa = smem + (it & 1) * 16384;
        const char* sb = sa + 8192;
        bf16x8 af[4], bfr[4];
        #pragma unroll
        for (int mi = 0; mi < 4; ++mi) {
            const int m = wrow * 64 + mi * 16 + lr16;
            af[mi] = *(const bf16x8*)(sa + m * 64 + ((qk ^ (m & 3)) * 16));
        }
        #pragma unroll
        for (int ni = 0; ni < 4; ++ni) {
            const int n = wcol * 64 + ni * 16 + lr16;
            bfr[ni] = *(const bf16x8*)(sb + n * 64 + ((qk ^ (n & 3)) * 16));
        }
        #pragma unroll
        for (int mi = 0; mi < 4; ++mi)
            #pragma unroll
            for (int ni = 0; ni < 4; ++ni)
                acc[mi][ni] = __builtin_amdgcn_mfma_f32_16x16x32_bf16(
                    af[mi], bfr[ni], acc[mi][ni], 0, 0, 0);
    }
}

__global__ __launch_bounds__(256) void gemm_out_kernel(
    const short* __restrict__ corebf, const short* __restrict__ wo_bf,
    const float* __restrict__ b_out, float* __restrict__ C, int M)
{
    __shared__ __align__(16) char smem[36864];
    const int t = threadIdx.x;
    const int wave = t >> 6, lane = t & 63;
    const int lr16 = lane & 15, qk = lane >> 4;
    const int wrow = wave & 1, wcol = wave >> 1;
    const int bm = blockIdx.x * 128, bn = blockIdx.y * 128;

    f32x4 acc[4][4] = {};
    gemm_kloop_bf16(corebf, wo_bf, bm, bn, smem, acc, t, wave, lane);

    const int colbase = bn + wcol * 64;
    float bv[4];
    #pragma unroll
    for (int ni = 0; ni < 4; ++ni) bv[ni] = b_out[colbase + ni * 16 + lr16];
    float* ep = (float*)(smem + wave * 8704);
    #pragma unroll
    for (int p = 0; p < 2; ++p) {
        __syncthreads();
        #pragma unroll
        for (int mh = 0; mh < 2; ++mh) {
            const int mi = p * 2 + mh;
            #pragma unroll
            for (int ni = 0; ni < 4; ++ni)
                #pragma unroll
                for (int r = 0; r < 4; ++r)
                    ep[(mh * 16 + qk * 4 + r) * 68 + ni * 16 + lr16] =
                        acc[mi][ni][r] + bv[ni];
        }
        __syncthreads();
        const int er = lane >> 4, ec = (lane & 15) * 4;
        #pragma unroll
        for (int j = 0; j < 8; ++j) {
            const int r = j * 4 + er;
            const float4 vv = *(const float4*)&ep[r * 68 + ec];
            const int grow = bm + wrow * 64 + p * 32 + r;
            if (grow < M)
                *(float4*)&C[(size_t)grow * 256 + colbase + ec] = vv;
        }
    }
}

// ---------------- MSDA sampling core ----------------
// Block = 8 queries x 32 lanes. Taps packed idx|fp16w, stored 68-u32 stride
// (16B-aligned rows) so phase 2 reads 4 taps per ds_read_b128.
__global__ __launch_bounds__(256) void msda_core_kernel(
    const __half* __restrict__ vproj,   // (bs*nv, 256) fp16
    const float* __restrict__ refp,     // (M, 8)
    const __half* __restrict__ qo,      // (M_PAD, 384): [0,256)=offsets, [256,384)=logits
    short* __restrict__ core,           // (M_PAD, 256) bf16
    int nq, int nv, int M)
{
    const int bq0 = blockIdx.x * NQPB;
    const int t = threadIdx.x;

    __shared__ float s_w[NQPB * 128];
    __shared__ float s_ref[NQPB * 8];
    __shared__ __align__(16) unsigned int s_tap[NQPB * 8][68];  // 272B rows: aligned + bank-spread

    #pragma unroll
    for (int i = 0; i < 4; ++i) {
        const int s = t + i * 256;          // [0,1024)
        const int q = s >> 7, r = s & 127;
        s_w[s] = __half2float(qo[(size_t)(bq0 + q) * 384 + 256 + r]);
    }
    if (t < NQPB * 8) {
        const int gq = min(bq0 + (t >> 3), M - 1);
        s_ref[t] = refp[(size_t)gq * 8 + (t & 7)];
    }
    __syncthreads();

    // softmax over 16 per (q,h)
    if (t < NQPB * 8) {
        const int base = (t >> 3) * 128 + (t & 7) * 16;
        float m = -1e30f;
        #pragma unroll
        for (int j = 0; j < 16; ++j) m = fmaxf(m, s_w[base + j]);
        float e[16]; float ssum = 0.f;
        #pragma unroll
        for (int j = 0; j < 16; ++j) { e[j] = expf(s_w[base + j] - m); ssum += e[j]; }
        const float inv = 1.f / ssum;
        #pragma unroll
        for (int j = 0; j < 16; ++j) s_w[base + j] = e[j] * inv;
    }
    __syncthreads();

    // phase 1: tap precompute — 1024 samples, 4 per thread
    #pragma unroll
    for (int i = 0; i < 4; ++i) {
        const int s = t + i * 256;
        const int q = s >> 7, r = s & 127;
        const int h = r >> 4, lp = r & 15, l = lp >> 2;
        const int gq = bq0 + q;             // < M_PAD: qo is padded
        const float2 off = __half22float2(*(const __half2*)&qo[(size_t)gq * 384 + r * 2]);
        const float rx = s_ref[q * 8 + l * 2];
        const float ry = s_ref[q * 8 + l * 2 + 1];
        const int W = c_W[l], H = c_H[l], st = c_ST[l];
        const float fW = (float)W, fH = (float)H;
        const float lx = (rx + off.x / fW) * fW - 0.5f;
        const float ly = (ry + off.y / fH) * fH - 0.5f;
        const float x0f = floorf(lx), y0f = floorf(ly);
        const float fx = lx - x0f, fy = ly - y0f;
        const int x0 = (int)x0f, y0 = (int)y0f;
        const float aw = s_w[s];
        const float wx[2] = {1.f - fx, fx};
        const float wy[2] = {1.f - fy, fy};
        #pragma unroll
        for (int dy = 0; dy < 2; ++dy) {
            #pragma unroll
            for (int dx = 0; dx < 2; ++dx) {
                const int xi = x0 + dx, yi = y0 + dy;
                const bool ok = (xi >= 0) & (xi < W) & (yi >= 0) & (yi < H);
                const unsigned int idx = ok ? (unsigned int)(st + yi * W + xi) : 0u;
                const float w = ok ? aw * wy[dy] * wx[dx] : 0.f;
                const unsigned int pw = (unsigned int)__half_as_ushort(__float2half(w));
                s_tap[q * 8 + h][lp * 4 + dy * 2 + dx] = idx | (pw << 16);
            }
        }
    }
    __syncthreads();

    // phase 2: gather + weighted sum. 32 lanes/query: h = 0..7, c8 = 0..3.
    const int q   = t >> 5;
    const int l32 = t & 31;
    const int h   = l32 >> 2;
    const int c8  = l32 & 3;
    const int gq  = bq0 + q;
    const int b   = (gq >= nq) ? 1 : 0;
    const __half* __restrict__ vb = vproj + (size_t)b * nv * EMBED + h * 32 + c8 * 8;
    const uint4* __restrict__ tapq = (const uint4*)s_tap[q * 8 + h];

    float a[8] = {0.f, 0.f, 0.f, 0.f, 0.f, 0.f, 0.f, 0.f};
    uint4 tq = tapq[0];
    #pragma unroll
    for (int g = 0; g < 16; ++g) {
        // 4 independent value loads for this tap group
        const int4 r0 = *(const int4*)(vb + (size_t)(tq.x & 0xFFFFu) * EMBED);
        const int4 r1 = *(const int4*)(vb + (size_t)(tq.y & 0xFFFFu) * EMBED);
        const int4 r2 = *(const int4*)(vb + (size_t)(tq.z & 0xFFFFu) * EMBED);
        const int4 r3 = *(const int4*)(vb + (size_t)(tq.w & 0xFFFFu) * EMBED);
        const uint4 tn = (g < 15) ? tapq[g + 1] : tq;   // prefetch next group's taps
        const float w0 = __half2float(__ushort_as_half((unsigned short)(tq.x >> 16)));
        const float w1 = __half2float(__ushort_as_half((unsigned short)(tq.y >> 16)));
        const float w2 = __half2float(__ushort_as_half((unsigned short)(tq.z >> 16)));
        const float w3 = __half2float(__ushort_as_half((unsigned short)(tq.w >> 16)));
        const __half* g0 = (const __half*)&r0;
        const __half* g1 = (const __half*)&r1;
        const __half* g2 = (const __half*)&r2;
        const __half* g3 = (const __half*)&r3;
        #pragma unroll
        for (int i = 0; i < 8; ++i) {
            a[i] = fmaf(w0, __half2float(g0[i]), a[i]);
            a[i] = fmaf(w1, __half2float(g1[i]), a[i]);
            a[i] = fmaf(w2, __half2float(g2[i]), a[i]);
            a[i] = fmaf(w3, __half2float(g3[i]), a[i]);
        }
        tq = tn;
    }

    if (gq < M) {
        __align__(16) short o[8];
        #pragma unroll
        for (int i = 0; i < 8; ++i) o[i] = f2bf(a[i]);
        *(int4*)&core[(size_t)gq * 256 + h * 32 + c8 * 8] = *(const int4*)o;
    }
}

// ---------------- launch ----------------
extern "C" void kernel_launch(void* const* d_in, const int* in_sizes, int n_in,
                              void* d_out, int out_size, void* d_ws, size_t ws_size,
                              hipStream_t stream) {
    const float* query  = (const float*)d_in[0];
    const float* refp   = (const float*)d_in[1];
    const float* value  = (const float*)d_in[2];
    const float* W_samp = (const float*)d_in[6];
    const float* b_samp = (const float*)d_in[7];
    const float* W_attn = (const float*)d_in[8];
    const float* b_attn = (const float*)d_in[9];
    const float* W_val  = (const float*)d_in[10];
    const float* b_val  = (const float*)d_in[11];
    const float* W_out  = (const float*)d_in[12];
    const float* b_out  = (const float*)d_in[13];
    float* out = (float*)d_out;

    const int M  = in_sizes[0] / EMBED;   // 26588
    const int nq = NV_PER_B;
    const int nv = NV_PER_B;
    const int Mp = M_PAD;

    // workspace carve-up (~48.5 MB)
    char* p = (char*)d_ws;
    short*  corebf = (short*)p;  p += (size_t)Mp * 256 * 2;
    __half* vproj  = (__half*)p; p += (size_t)Mp * 256 * 2;
    __half* qo     = (__half*)p; p += (size_t)Mp * 384 * 2;
    short*  wv_bf  = (short*)p;  p += 65536 * 2;
    short*  wcat   = (short*)p;  p += 98304 * 2;
    short*  wo_bf  = (short*)p;  p += 65536 * 2;
    float*  biascat= (float*)p;  p += 384 * 4;

    dim3 blk(256);

    wconv_kernel<<<dim3(96), blk, 0, stream>>>(
        W_val, W_samp, W_attn, W_out, b_samp, b_attn,
        wv_bf, wcat, wo_bf, biascat);

    const int mb = Mp / 128;  // 208
    proj_gemm_kernel<<<dim3(mb, 5), blk, 0, stream>>>(
        value, wv_bf, b_val, vproj, query, wcat, biascat, qo, M);

    msda_core_kernel<<<dim3((M + NQPB - 1) / NQPB), blk, 0, stream>>>(
        vproj, refp, qo, corebf, nq, nv, M);

    gemm_out_kernel<<<dim3(mb, 2), blk, 0, stream>>>(
        corebf, wo_bf, b_out, out, M);
}

// Round 6
// 210.874 us; speedup vs baseline: 1.9064x; 1.9064x over previous
//
#include <hip/hip_runtime.h>
#include <hip/hip_bf16.h>
#include <hip/hip_fp16.h>
#include <cstdint>
#include <cstddef>

// Problem constants (fixed by reference setup_inputs)
#define EMBED  256
#define NV_PER_B 13294
#define M_REAL  26588
#define M_PAD   26624          // 208 * 128
#define NQPB   8               // queries per msda block

// Spatial pyramid (structural constants from reference SHAPES)
__constant__ const int c_H[4]  = {100, 50, 25, 13};
__constant__ const int c_W[4]  = {100, 50, 25, 13};
__constant__ const int c_ST[4] = {0, 10000, 12500, 13125};

typedef __attribute__((ext_vector_type(8))) short bf16x8;
typedef __attribute__((ext_vector_type(4))) float f32x4;

__device__ inline short f2bf(float x) {
    __hip_bfloat16 h = __float2bfloat16(x);
    return *reinterpret_cast<short*>(&h);
}

// ---------------- tiny weight convert: fp32 -> bf16 + concat ----------------
__global__ __launch_bounds__(256) void wconv_kernel(
    const float* __restrict__ wv, const float* __restrict__ wsamp,
    const float* __restrict__ wattn, const float* __restrict__ wo,
    const float* __restrict__ bsamp, const float* __restrict__ battn,
    short* __restrict__ wv_bf, short* __restrict__ wcat_bf,
    short* __restrict__ wo_bf, float* __restrict__ bias_cat)
{
    const int i = blockIdx.x * 256 + threadIdx.x;
    if (i < 16384) {  // W_val, W_out: 65536/4 float4s each
        float4 a = ((const float4*)wv)[i];
        float4 c = ((const float4*)wo)[i];
        ((short4*)wv_bf)[i] = make_short4(f2bf(a.x), f2bf(a.y), f2bf(a.z), f2bf(a.w));
        ((short4*)wo_bf)[i] = make_short4(f2bf(c.x), f2bf(c.y), f2bf(c.z), f2bf(c.w));
    }
    if (i < 24576) {  // W_cat = [W_samp(256x256); W_attn(128x256)]
        float4 a = (i < 16384) ? ((const float4*)wsamp)[i]
                               : ((const float4*)wattn)[i - 16384];
        ((short4*)wcat_bf)[i] = make_short4(f2bf(a.x), f2bf(a.y), f2bf(a.z), f2bf(a.w));
    }
    if (i < 96) {     // bias_cat = [b_samp(256); b_attn(128)]
        float4 a = (i < 64) ? ((const float4*)bsamp)[i]
                            : ((const float4*)battn)[i - 64];
        ((float4*)bias_cat)[i] = a;
    }
}

// ---------------- proj GEMM: fp32 A read + in-register bf16 cvt ----------------
// 128x128 tile, K=256, 8 K-iters double-buffered. A: buffer->VGPR->cvt->ds_write
// (XOR-swizzled [row][4 slots of 16B] layout); B: global_load_lds bf16.
// grid.y: 0,1 -> vproj(256 cols); 2,3 -> qo samp cols; 4 -> qo attn cols.
__global__ __launch_bounds__(256) void proj_gemm_kernel(
    const float* __restrict__ value, const short* __restrict__ wv_bf,
    const float* __restrict__ b_val, __half* __restrict__ vproj,
    const float* __restrict__ query, const short* __restrict__ wcat_bf,
    const float* __restrict__ bias_cat, __half* __restrict__ qo, int M)
{
    constexpr int K = 256;
    __shared__ __align__(16) char smem[36864];   // 2 stages x (A 8KB + B 8KB); epilogue reuse

    const int t = threadIdx.x;
    const int wave = t >> 6, lane = t & 63;
    const int lr16 = lane & 15, qk = lane >> 4;
    const int wrow = wave & 1, wcol = wave >> 1;
    const int y = blockIdx.y;
    const int bm = blockIdx.x * 128;

    const float* A; const short* Wt; const float* bias; __half* Cc; int Nst, bn;
    if (y < 2) { A = value; Wt = wv_bf;   bias = b_val;    Cc = vproj; Nst = 256; bn = y * 128; }
    else       { A = query; Wt = wcat_bf; bias = bias_cat; Cc = qo;    Nst = 384; bn = (y - 2) * 128; }

    // A staging coords: thread t -> row = t>>1 (0..127), khalf = (t&1)*16
    const int arow = t >> 1;
    const int akh  = (t & 1) * 16;
    const size_t abase = (size_t)min(bm + arow, M - 1) * K + akh;
    const int aslot0 = ((t & 1) * 2 + 0) ^ (arow & 3);
    const int aslot1 = ((t & 1) * 2 + 1) ^ (arow & 3);

    // B staging coords (global_load_lds)
    const int brow0 = t >> 2, brow1 = brow0 + 64;
    const int kbl  = t & 3;
    const int kbg0 = kbl ^ (brow0 & 3);
    const int kbg1 = kbl ^ (brow1 & 3);
    const size_t b0 = (size_t)(bn + brow0) * K + kbg0 * 8;
    const size_t b1 = (size_t)(bn + brow1) * K + kbg1 * 8;

    f32x4 acc[4][4] = {};
    float4 areg[4];

    auto loadA = [&](int k0) {
        #pragma unroll
        for (int i = 0; i < 4; ++i)
            areg[i] = *(const float4*)&A[abase + k0 + i * 4];
    };
    auto issueB = [&](int stage, int k0) {
        char* sb = smem + stage * 16384 + 8192 + wave * 1024;  // wave-uniform base
        __builtin_amdgcn_global_load_lds(
            (const __attribute__((address_space(1))) void*)(Wt + b0 + k0),
            (__attribute__((address_space(3))) void*)(sb), 16, 0, 0);
        __builtin_amdgcn_global_load_lds(
            (const __attribute__((address_space(1))) void*)(Wt + b1 + k0),
            (__attribute__((address_space(3))) void*)(sb + 4096), 16, 0, 0);
    };
    auto writeA = [&](int stage) {
        char* sa = smem + stage * 16384;
        __align__(16) short h8a[8], h8b[8];
        const float* f = (const float*)areg;
        #pragma unroll
        for (int i = 0; i < 8; ++i) { h8a[i] = f2bf(f[i]); h8b[i] = f2bf(f[8 + i]); }
        *(bf16x8*)(sa + arow * 64 + aslot0 * 16) = *(const bf16x8*)h8a;
        *(bf16x8*)(sa + arow * 64 + aslot1 * 16) = *(const bf16x8*)h8b;
    };

    loadA(0);
    issueB(0, 0);
    writeA(0);
    #pragma unroll
    for (int it = 0; it < 8; ++it) {
        __syncthreads();   // stage it&1 resident (A ds_writes ordered; B vmcnt drained)
        if (it + 1 < 8) {
            loadA((it + 1) * 32);
            issueB((it + 1) & 1, (it + 1) * 32);
        }
        const char* sa = smem + (it & 1) * 16384;
        const char* sb = sa + 8192;
        bf16x8 af[4], bfr[4];
        #pragma unroll
        for (int mi = 0; mi < 4; ++mi) {
            const int m = wrow * 64 + mi * 16 + lr16;
            af[mi] = *(const bf16x8*)(sa + m * 64 + ((qk ^ (m & 3)) * 16));
        }
        #pragma unroll
        for (int ni = 0; ni < 4; ++ni) {
            const int n = wcol * 64 + ni * 16 + lr16;
            bfr[ni] = *(const bf16x8*)(sb + n * 64 + ((qk ^ (n & 3)) * 16));
        }
        #pragma unroll
        for (int mi = 0; mi < 4; ++mi)
            #pragma unroll
            for (int ni = 0; ni < 4; ++ni)
                acc[mi][ni] = __builtin_amdgcn_mfma_f32_16x16x32_bf16(
                    af[mi], bfr[ni], acc[mi][ni], 0, 0, 0);
        if (it + 1 < 8) writeA((it + 1) & 1);
    }

    // epilogue: per-wave LDS transpose (64x64 fp16, stride 72 halves) -> dwordx4 stores
    __syncthreads();
    __half* ep = (__half*)(smem + wave * 9216);
    const int colbase = bn + wcol * 64;
    float bv[4];
    #pragma unroll
    for (int ni = 0; ni < 4; ++ni) bv[ni] = bias[colbase + ni * 16 + lr16];
    #pragma unroll
    for (int mi = 0; mi < 4; ++mi)
        #pragma unroll
        for (int ni = 0; ni < 4; ++ni)
            #pragma unroll
            for (int r = 0; r < 4; ++r)
                ep[(mi * 16 + qk * 4 + r) * 72 + ni * 16 + lr16] =
                    __float2half(acc[mi][ni][r] + bv[ni]);
    __syncthreads();
    const int er = lane >> 3, ec = (lane & 7) * 8;
    #pragma unroll
    for (int pass = 0; pass < 8; ++pass) {
        const int r = pass * 8 + er;
        const int4 vv = *(const int4*)&ep[r * 72 + ec];
        const int grow = bm + wrow * 64 + r;
        *(int4*)&Cc[(size_t)grow * Nst + colbase + ec] = vv;
    }
}

// ---------------- final GEMM: core(bf16) @ W_out^T + b_out -> fp32 d_out ----------------
__device__ __forceinline__ void gemm_kloop_bf16(
    const short* __restrict__ A, const short* __restrict__ Wt,
    int bm, int bn, char* smem, f32x4 (&acc)[4][4],
    int t, int wave, int lane)
{
    constexpr int K = 256;
    const int row0 = t >> 2, row1 = row0 + 64;
    const int kbl  = t & 3;
    const int kbg0 = kbl ^ (row0 & 3);
    const int kbg1 = kbl ^ (row1 & 3);
    const size_t a0 = (size_t)(bm + row0) * K + kbg0 * 8;
    const size_t a1 = (size_t)(bm + row1) * K + kbg1 * 8;
    const size_t b0 = (size_t)(bn + row0) * K + kbg0 * 8;
    const size_t b1 = (size_t)(bn + row1) * K + kbg1 * 8;
    const int lr16 = lane & 15, qk = lane >> 4;
    const int wrow = wave & 1, wcol = wave >> 1;

    auto issue = [&](int stage, int k0) {
        char* sa = smem + stage * 16384 + wave * 1024;
        char* sb = sa + 8192;
        __builtin_amdgcn_global_load_lds(
            (const __attribute__((address_space(1))) void*)(A + a0 + k0),
            (__attribute__((address_space(3))) void*)(sa), 16, 0, 0);
        __builtin_amdgcn_global_load_lds(
            (const __attribute__((address_space(1))) void*)(A + a1 + k0),
            (__attribute__((address_space(3))) void*)(sa + 4096), 16, 0, 0);
        __builtin_amdgcn_global_load_lds(
            (const __attribute__((address_space(1))) void*)(Wt + b0 + k0),
            (__attribute__((address_space(3))) void*)(sb), 16, 0, 0);
        __builtin_amdgcn_global_load_lds(
            (const __attribute__((address_space(1))) void*)(Wt + b1 + k0),
            (__attribute__((address_space(3))) void*)(sb + 4096), 16, 0, 0);
    };

    issue(0, 0);
    #pragma unroll
    for (int it = 0; it < 8; ++it) {
        __syncthreads();
        if (it + 1 < 8) issue((it + 1) & 1, (it + 1) * 32);
        const char* sa = smem + (it & 1) * 16384;
        const char* sb = sa + 8192;
        bf16x8 af[4], bfr[4];
        #pragma unroll
        for (int mi = 0; mi < 4; ++mi) {
            const int m = wrow * 64 + mi * 16 + lr16;
            af[mi] = *(const bf16x8*)(sa + m * 64 + ((qk ^ (m & 3)) * 16));
        }
        #pragma unroll
        for (int ni = 0; ni < 4; ++ni) {
            const int n = wcol * 64 + ni * 16 + lr16;
            bfr[ni] = *(const bf16x8*)(sb + n * 64 + ((qk ^ (n & 3)) * 16));
        }
        #pragma unroll
        for (int mi = 0; mi < 4; ++mi)
            #pragma unroll
            for (int ni = 0; ni < 4; ++ni)
                acc[mi][ni] = __builtin_amdgcn_mfma_f32_16x16x32_bf16(
                    af[mi], bfr[ni], acc[mi][ni], 0, 0, 0);
    }
}

__global__ __launch_bounds__(256) void gemm_out_kernel(
    const short* __restrict__ corebf, const short* __restrict__ wo_bf,
    const float* __restrict__ b_out, float* __restrict__ C, int M)
{
    __shared__ __align__(16) char smem[36864];
    const int t = threadIdx.x;
    const int wave = t >> 6, lane = t & 63;
    const int lr16 = lane & 15, qk = lane >> 4;
    const int wrow = wave & 1, wcol = wave >> 1;
    const int bm = blockIdx.x * 128, bn = blockIdx.y * 128;

    f32x4 acc[4][4] = {};
    gemm_kloop_bf16(corebf, wo_bf, bm, bn, smem, acc, t, wave, lane);

    const int colbase = bn + wcol * 64;
    float bv[4];
    #pragma unroll
    for (int ni = 0; ni < 4; ++ni) bv[ni] = b_out[colbase + ni * 16 + lr16];
    float* ep = (float*)(smem + wave * 8704);
    #pragma unroll
    for (int p = 0; p < 2; ++p) {
        __syncthreads();
        #pragma unroll
        for (int mh = 0; mh < 2; ++mh) {
            const int mi = p * 2 + mh;
            #pragma unroll
            for (int ni = 0; ni < 4; ++ni)
                #pragma unroll
                for (int r = 0; r < 4; ++r)
                    ep[(mh * 16 + qk * 4 + r) * 68 + ni * 16 + lr16] =
                        acc[mi][ni][r] + bv[ni];
        }
        __syncthreads();
        const int er = lane >> 4, ec = (lane & 15) * 4;
        #pragma unroll
        for (int j = 0; j < 8; ++j) {
            const int r = j * 4 + er;
            const float4 vv = *(const float4*)&ep[r * 68 + ec];
            const int grow = bm + wrow * 64 + p * 32 + r;
            if (grow < M)
                *(float4*)&C[(size_t)grow * 256 + colbase + ec] = vv;
        }
    }
}

// ---------------- MSDA sampling core ----------------
// Block = 8 queries x 32 lanes. Taps packed idx|fp16w in 68-u32 stride rows
// (16B-aligned). Phase 2: uint4 tap reads (4 taps/ds_read_b128), unroll 2
// (bounded ILP: <=8 gathers in flight — round 5's full unroll spilled at 256 VGPR).
__global__ __launch_bounds__(256, 4) void msda_core_kernel(
    const __half* __restrict__ vproj,   // (bs*nv, 256) fp16
    const float* __restrict__ refp,     // (M, 8)
    const __half* __restrict__ qo,      // (M_PAD, 384): [0,256)=offsets, [256,384)=logits
    short* __restrict__ core,           // (M_PAD, 256) bf16
    int nq, int nv, int M)
{
    const int bq0 = blockIdx.x * NQPB;
    const int t = threadIdx.x;

    __shared__ float s_w[NQPB * 128];
    __shared__ float s_ref[NQPB * 8];
    __shared__ __align__(16) unsigned int s_tap[NQPB * 8][68];  // 272B rows: aligned + bank-spread

    #pragma unroll
    for (int i = 0; i < 4; ++i) {
        const int s = t + i * 256;          // [0,1024)
        const int q = s >> 7, r = s & 127;
        s_w[s] = __half2float(qo[(size_t)(bq0 + q) * 384 + 256 + r]);
    }
    if (t < NQPB * 8) {
        const int gq = min(bq0 + (t >> 3), M - 1);
        s_ref[t] = refp[(size_t)gq * 8 + (t & 7)];
    }
    __syncthreads();

    // softmax over 16 per (q,h)
    if (t < NQPB * 8) {
        const int base = (t >> 3) * 128 + (t & 7) * 16;
        float m = -1e30f;
        #pragma unroll
        for (int j = 0; j < 16; ++j) m = fmaxf(m, s_w[base + j]);
        float e[16]; float ssum = 0.f;
        #pragma unroll
        for (int j = 0; j < 16; ++j) { e[j] = expf(s_w[base + j] - m); ssum += e[j]; }
        const float inv = 1.f / ssum;
        #pragma unroll
        for (int j = 0; j < 16; ++j) s_w[base + j] = e[j] * inv;
    }
    __syncthreads();

    // phase 1: tap precompute — 1024 samples, 4 per thread
    #pragma unroll
    for (int i = 0; i < 4; ++i) {
        const int s = t + i * 256;
        const int q = s >> 7, r = s & 127;
        const int h = r >> 4, lp = r & 15, l = lp >> 2;
        const int gq = bq0 + q;             // < M_PAD: qo is padded
        const float2 off = __half22float2(*(const __half2*)&qo[(size_t)gq * 384 + r * 2]);
        const float rx = s_ref[q * 8 + l * 2];
        const float ry = s_ref[q * 8 + l * 2 + 1];
        const int W = c_W[l], H = c_H[l], st = c_ST[l];
        const float fW = (float)W, fH = (float)H;
        const float lx = (rx + off.x / fW) * fW - 0.5f;
        const float ly = (ry + off.y / fH) * fH - 0.5f;
        const float x0f = floorf(lx), y0f = floorf(ly);
        const float fx = lx - x0f, fy = ly - y0f;
        const int x0 = (int)x0f, y0 = (int)y0f;
        const float aw = s_w[s];
        const float wx[2] = {1.f - fx, fx};
        const float wy[2] = {1.f - fy, fy};
        #pragma unroll
        for (int dy = 0; dy < 2; ++dy) {
            #pragma unroll
            for (int dx = 0; dx < 2; ++dx) {
                const int xi = x0 + dx, yi = y0 + dy;
                const bool ok = (xi >= 0) & (xi < W) & (yi >= 0) & (yi < H);
                const unsigned int idx = ok ? (unsigned int)(st + yi * W + xi) : 0u;
                const float w = ok ? aw * wy[dy] * wx[dx] : 0.f;
                const unsigned int pw = (unsigned int)__half_as_ushort(__float2half(w));
                s_tap[q * 8 + h][lp * 4 + dy * 2 + dx] = idx | (pw << 16);
            }
        }
    }
    __syncthreads();

    // phase 2: gather + weighted sum. 32 lanes/query: h = 0..7, c8 = 0..3.
    const int q   = t >> 5;
    const int l32 = t & 31;
    const int h   = l32 >> 2;
    const int c8  = l32 & 3;
    const int gq  = bq0 + q;
    const int b   = (gq >= nq) ? 1 : 0;
    const __half* __restrict__ vb = vproj + (size_t)b * nv * EMBED + h * 32 + c8 * 8;
    const uint4* __restrict__ tapq = (const uint4*)s_tap[q * 8 + h];

    float a[8] = {0.f, 0.f, 0.f, 0.f, 0.f, 0.f, 0.f, 0.f};
    #pragma unroll 2
    for (int g = 0; g < 16; ++g) {
        const uint4 tq = tapq[g];
        const int4 r0 = *(const int4*)(vb + (size_t)(tq.x & 0xFFFFu) * EMBED);
        const int4 r1 = *(const int4*)(vb + (size_t)(tq.y & 0xFFFFu) * EMBED);
        const int4 r2 = *(const int4*)(vb + (size_t)(tq.z & 0xFFFFu) * EMBED);
        const int4 r3 = *(const int4*)(vb + (size_t)(tq.w & 0xFFFFu) * EMBED);
        const float w0 = __half2float(__ushort_as_half((unsigned short)(tq.x >> 16)));
        const float w1 = __half2float(__ushort_as_half((unsigned short)(tq.y >> 16)));
        const float w2 = __half2float(__ushort_as_half((unsigned short)(tq.z >> 16)));
        const float w3 = __half2float(__ushort_as_half((unsigned short)(tq.w >> 16)));
        const __half* g0 = (const __half*)&r0;
        const __half* g1 = (const __half*)&r1;
        const __half* g2 = (const __half*)&r2;
        const __half* g3 = (const __half*)&r3;
        #pragma unroll
        for (int i = 0; i < 8; ++i) {
            a[i] = fmaf(w0, __half2float(g0[i]), a[i]);
            a[i] = fmaf(w1, __half2float(g1[i]), a[i]);
            a[i] = fmaf(w2, __half2float(g2[i]), a[i]);
            a[i] = fmaf(w3, __half2float(g3[i]), a[i]);
        }
    }

    if (gq < M) {
        __align__(16) short o[8];
        #pragma unroll
        for (int i = 0; i < 8; ++i) o[i] = f2bf(a[i]);
        *(int4*)&core[(size_t)gq * 256 + h * 32 + c8 * 8] = *(const int4*)o;
    }
}

// ---------------- launch ----------------
extern "C" void kernel_launch(void* const* d_in, const int* in_sizes, int n_in,
                              void* d_out, int out_size, void* d_ws, size_t ws_size,
                              hipStream_t stream) {
    const float* query  = (const float*)d_in[0];
    const float* refp   = (const float*)d_in[1];
    const float* value  = (const float*)d_in[2];
    const float* W_samp = (const float*)d_in[6];
    const float* b_samp = (const float*)d_in[7];
    const float* W_attn = (const float*)d_in[8];
    const float* b_attn = (const float*)d_in[9];
    const float* W_val  = (const float*)d_in[10];
    const float* b_val  = (const float*)d_in[11];
    const float* W_out  = (const float*)d_in[12];
    const float* b_out  = (const float*)d_in[13];
    float* out = (float*)d_out;

    const int M  = in_sizes[0] / EMBED;   // 26588
    const int nq = NV_PER_B;
    const int nv = NV_PER_B;
    const int Mp = M_PAD;

    // workspace carve-up (~48.5 MB)
    char* p = (char*)d_ws;
    short*  corebf = (short*)p;  p += (size_t)Mp * 256 * 2;
    __half* vproj  = (__half*)p; p += (size_t)Mp * 256 * 2;
    __half* qo     = (__half*)p; p += (size_t)Mp * 384 * 2;
    short*  wv_bf  = (short*)p;  p += 65536 * 2;
    short*  wcat   = (short*)p;  p += 98304 * 2;
    short*  wo_bf  = (short*)p;  p += 65536 * 2;
    float*  biascat= (float*)p;  p += 384 * 4;

    dim3 blk(256);

    wconv_kernel<<<dim3(96), blk, 0, stream>>>(
        W_val, W_samp, W_attn, W_out, b_samp, b_attn,
        wv_bf, wcat, wo_bf, biascat);

    const int mb = Mp / 128;  // 208
    proj_gemm_kernel<<<dim3(mb, 5), blk, 0, stream>>>(
        value, wv_bf, b_val, vproj, query, wcat, biascat, qo, M);

    msda_core_kernel<<<dim3((M + NQPB - 1) / NQPB), blk, 0, stream>>>(
        vproj, refp, qo, corebf, nq, nv, M);

    gemm_out_kernel<<<dim3(mb, 2), blk, 0, stream>>>(
        corebf, wo_bf, b_out, out, M);
}

// Round 7
// 206.728 us; speedup vs baseline: 1.9446x; 1.0201x over previous
//
#include <hip/hip_runtime.h>
#include <hip/hip_fp16.h>
#include <cstdint>
#include <cstddef>

// Problem constants (fixed by reference setup_inputs)
#define EMBED  256
#define NV_PER_B 13294
#define M_PAD   26624          // 208 * 128
#define NQPB   8               // queries per msda block

// Spatial pyramid (structural constants from reference SHAPES)
__constant__ const int c_H[4]  = {100, 50, 25, 13};
__constant__ const int c_W[4]  = {100, 50, 25, 13};
__constant__ const int c_ST[4] = {0, 10000, 12500, 13125};

typedef _Float16 f16x8 __attribute__((ext_vector_type(8)));
typedef float f32x4 __attribute__((ext_vector_type(4)));

#define GLDS(g, l) __builtin_amdgcn_global_load_lds( \
    (const __attribute__((address_space(1))) void*)(g), \
    (__attribute__((address_space(3))) void*)(l), 16, 0, 0)

__device__ inline unsigned short f2hu(float x) { return __half_as_ushort(__float2half(x)); }

// ---------------- fp32 -> fp16 conversion: q, v (padded) + weights + concat ----------------
__global__ __launch_bounds__(256) void convert_kernel(
    const float* __restrict__ q,  const float* __restrict__ v,
    const float* __restrict__ wv, const float* __restrict__ wsamp,
    const float* __restrict__ wattn, const float* __restrict__ wo,
    const float* __restrict__ bsamp, const float* __restrict__ battn,
    __half* __restrict__ q_h, __half* __restrict__ v_h,
    __half* __restrict__ wv_h, __half* __restrict__ wcat_h,
    __half* __restrict__ wo_h, float* __restrict__ bias_cat,
    int n_real4, int n_pad4)
{
    const int i = blockIdx.x * 256 + threadIdx.x;
    if (i < n_pad4) {
        float4 a = make_float4(0.f, 0.f, 0.f, 0.f);
        float4 b = make_float4(0.f, 0.f, 0.f, 0.f);
        if (i < n_real4) {
            a = ((const float4*)q)[i];
            b = ((const float4*)v)[i];
        }
        ((ushort4*)q_h)[i] = make_ushort4(f2hu(a.x), f2hu(a.y), f2hu(a.z), f2hu(a.w));
        ((ushort4*)v_h)[i] = make_ushort4(f2hu(b.x), f2hu(b.y), f2hu(b.z), f2hu(b.w));
    }
    if (i < 16384) {  // W_val, W_out
        float4 a = ((const float4*)wv)[i];
        float4 c = ((const float4*)wo)[i];
        ((ushort4*)wv_h)[i] = make_ushort4(f2hu(a.x), f2hu(a.y), f2hu(a.z), f2hu(a.w));
        ((ushort4*)wo_h)[i] = make_ushort4(f2hu(c.x), f2hu(c.y), f2hu(c.z), f2hu(c.w));
    }
    if (i < 24576) {  // W_cat = [W_samp(256x256); W_attn(128x256)]
        float4 a = (i < 16384) ? ((const float4*)wsamp)[i]
                               : ((const float4*)wattn)[i - 16384];
        ((ushort4*)wcat_h)[i] = make_ushort4(f2hu(a.x), f2hu(a.y), f2hu(a.z), f2hu(a.w));
    }
    if (i < 96) {     // bias_cat = [b_samp(256); b_attn(128)]
        float4 a = (i < 64) ? ((const float4*)bsamp)[i]
                            : ((const float4*)battn)[i - 64];
        ((float4*)bias_cat)[i] = a;
    }
}

// ---------------- barrier-free per-wave GEMM K-loop ----------------
// Wave owns a 64x64 tile. 2 wave-private LDS stages of (A 4KB + B 4KB).
// Explicit s_waitcnt vmcnt(N) replaces __syncthreads: no vmcnt(0) barrier drain.
// Natural [row][32k] layout: each frag ds_read_b128 covers a contiguous 1KB
// row-group -> conflict-free, no XOR swizzle needed.
__device__ __forceinline__ void wave_kloop(
    const __half* __restrict__ A, const __half* __restrict__ Wt,
    size_t aoff, size_t boff, char* myst, f32x4 (&acc)[4][4],
    int lr16, int qk)
{
    auto issue = [&](int stage, int kc) {
        char* sa = myst + stage * 8192;
        const __half* ap = A + aoff + kc * 32;
        const __half* bp = Wt + boff + kc * 32;
        #pragma unroll
        for (int g = 0; g < 4; ++g) GLDS(ap + g * (16 * 256), sa + g * 1024);
        #pragma unroll
        for (int g = 0; g < 4; ++g) GLDS(bp + g * (16 * 256), sa + 4096 + g * 1024);
    };

    issue(0, 0);
    issue(1, 1);
    #pragma unroll
    for (int it = 0; it < 8; ++it) {
        if (it < 7) asm volatile("s_waitcnt vmcnt(8)" ::: "memory");
        else        asm volatile("s_waitcnt vmcnt(0)" ::: "memory");
        const char* sa = myst + (it & 1) * 8192;
        f16x8 af[4], bfr[4];
        #pragma unroll
        for (int mi = 0; mi < 4; ++mi)
            af[mi] = *(const f16x8*)(sa + (mi * 16 + lr16) * 64 + qk * 16);
        #pragma unroll
        for (int ni = 0; ni < 4; ++ni)
            bfr[ni] = *(const f16x8*)(sa + 4096 + (ni * 16 + lr16) * 64 + qk * 16);
        asm volatile("s_waitcnt lgkmcnt(0)" ::: "memory");  // frags in VGPRs before DMA overwrite
        if (it + 2 < 8) issue(it & 1, it + 2);
        #pragma unroll
        for (int mi = 0; mi < 4; ++mi)
            #pragma unroll
            for (int ni = 0; ni < 4; ++ni)
                acc[mi][ni] = __builtin_amdgcn_mfma_f32_16x16x32_f16(
                    af[mi], bfr[ni], acc[mi][ni], 0, 0, 0);
    }
}

// ---------------- proj GEMM: value->vproj (y=0,1) and query->qo (y=2,3,4) ----------------
__global__ __launch_bounds__(256) void proj_gemm_kernel(
    const __half* __restrict__ v_h, const __half* __restrict__ wv_h,
    const float* __restrict__ b_val, __half* __restrict__ vproj,
    const __half* __restrict__ q_h, const __half* __restrict__ wcat_h,
    const float* __restrict__ bias_cat, __half* __restrict__ qo)
{
    __shared__ __align__(16) char smem[65536];   // 4 waves x 2 stages x 8KB
    const int t = threadIdx.x;
    const int wave = t >> 6, lane = t & 63;
    const int lr16 = lane & 15, qk = lane >> 4;
    const int wrow = wave & 1, wcol = wave >> 1;
    const int y = blockIdx.y;
    const int bm = blockIdx.x * 128;

    const __half* A; const __half* Wt; const float* bias; __half* Cc; int Nst, bn;
    if (y < 2) { A = v_h; Wt = wv_h;   bias = b_val;    Cc = vproj; Nst = 256; bn = y * 128; }
    else       { A = q_h; Wt = wcat_h; bias = bias_cat; Cc = qo;    Nst = 384; bn = (y - 2) * 128; }

    char* myst = smem + wave * 16384;
    const int srow = lane >> 2, skb = lane & 3;
    const size_t aoff = (size_t)(bm + wrow * 64 + srow) * 256 + skb * 8;
    const size_t boff = (size_t)(bn + wcol * 64 + srow) * 256 + skb * 8;

    f32x4 acc[4][4] = {};
    wave_kloop(A, Wt, aoff, boff, myst, acc, lr16, qk);

    // wave-private epilogue: 64x64 fp16 transpose (stride 72 halves) -> dwordx4 stores
    const int colbase = bn + wcol * 64;
    float bv[4];
    #pragma unroll
    for (int ni = 0; ni < 4; ++ni) bv[ni] = bias[colbase + ni * 16 + lr16];
    __half* ep = (__half*)myst;
    #pragma unroll
    for (int mi = 0; mi < 4; ++mi)
        #pragma unroll
        for (int ni = 0; ni < 4; ++ni)
            #pragma unroll
            for (int r = 0; r < 4; ++r)
                ep[(mi * 16 + qk * 4 + r) * 72 + ni * 16 + lr16] =
                    __float2half(acc[mi][ni][r] + bv[ni]);
    const int er = lane >> 3, ec = (lane & 7) * 8;
    #pragma unroll
    for (int pass = 0; pass < 8; ++pass) {
        const int r = pass * 8 + er;
        const int4 vv = *(const int4*)&ep[r * 72 + ec];
        const int grow = bm + wrow * 64 + r;
        *(int4*)&Cc[(size_t)grow * Nst + colbase + ec] = vv;
    }
}

// ---------------- out GEMM: core(fp16) @ W_out^T + b_out -> fp32 d_out ----------------
__global__ __launch_bounds__(256) void gemm_out_kernel(
    const __half* __restrict__ core, const __half* __restrict__ wo_h,
    const float* __restrict__ b_out, float* __restrict__ C, int M)
{
    __shared__ __align__(16) char smem[65536];
    const int t = threadIdx.x;
    const int wave = t >> 6, lane = t & 63;
    const int lr16 = lane & 15, qk = lane >> 4;
    const int wrow = wave & 1, wcol = wave >> 1;
    const int bm = blockIdx.x * 128, bn = blockIdx.y * 128;

    char* myst = smem + wave * 16384;
    const int srow = lane >> 2, skb = lane & 3;
    const size_t aoff = (size_t)(bm + wrow * 64 + srow) * 256 + skb * 8;
    const size_t boff = (size_t)(bn + wcol * 64 + srow) * 256 + skb * 8;

    f32x4 acc[4][4] = {};
    wave_kloop(core, wo_h, aoff, boff, myst, acc, lr16, qk);

    // wave-private fp32 epilogue: 4 passes of 16 rows (stride 68 f32, 4.3KB)
    const int colbase = bn + wcol * 64;
    float bv[4];
    #pragma unroll
    for (int ni = 0; ni < 4; ++ni) bv[ni] = b_out[colbase + ni * 16 + lr16];
    float* ep = (float*)myst;
    const int er = lane >> 4, ec = (lane & 15) * 4;
    #pragma unroll
    for (int p = 0; p < 4; ++p) {   // pass p handles rows mi==p
        #pragma unroll
        for (int ni = 0; ni < 4; ++ni)
            #pragma unroll
            for (int r = 0; r < 4; ++r)
                ep[(qk * 4 + r) * 68 + ni * 16 + lr16] = acc[p][ni][r] + bv[ni];
        #pragma unroll
        for (int j = 0; j < 4; ++j) {
            const int r16 = j * 4 + er;
            const float4 vv = *(const float4*)&ep[r16 * 68 + ec];
            const int grow = bm + wrow * 64 + p * 16 + r16;
            if (grow < M)
                *(float4*)&C[(size_t)grow * 256 + colbase + ec] = vv;
        }
        asm volatile("s_waitcnt lgkmcnt(0)" ::: "memory");  // reads done before next pass overwrites
    }
}

// ---------------- MSDA sampling core ----------------
// Block = 8 queries x 32 lanes. Taps packed idx|fp16w in 68-u32 stride rows.
// Phase 2: uint4 tap reads + v_pk_fma_f16 accumulation (no cvt in hot loop).
__global__ __launch_bounds__(256, 4) void msda_core_kernel(
    const __half* __restrict__ vproj,   // (bs*nv, 256) fp16
    const float* __restrict__ refp,     // (M, 8)
    const __half* __restrict__ qo,      // (M_PAD, 384): [0,256)=offsets, [256,384)=logits
    __half* __restrict__ core,          // (M_PAD, 256) fp16
    int nq, int nv, int M)
{
    const int bq0 = blockIdx.x * NQPB;
    const int t = threadIdx.x;

    __shared__ float s_w[NQPB * 128];
    __shared__ float s_ref[NQPB * 8];
    __shared__ __align__(16) unsigned int s_tap[NQPB * 8][68];

    #pragma unroll
    for (int i = 0; i < 4; ++i) {
        const int s = t + i * 256;          // [0,1024)
        const int q = s >> 7, r = s & 127;
        s_w[s] = __half2float(qo[(size_t)(bq0 + q) * 384 + 256 + r]);
    }
    if (t < NQPB * 8) {
        const int gq = min(bq0 + (t >> 3), M - 1);
        s_ref[t] = refp[(size_t)gq * 8 + (t & 7)];
    }
    __syncthreads();

    // softmax over 16 per (q,h)
    if (t < NQPB * 8) {
        const int base = (t >> 3) * 128 + (t & 7) * 16;
        float m = -1e30f;
        #pragma unroll
        for (int j = 0; j < 16; ++j) m = fmaxf(m, s_w[base + j]);
        float e[16]; float ssum = 0.f;
        #pragma unroll
        for (int j = 0; j < 16; ++j) { e[j] = expf(s_w[base + j] - m); ssum += e[j]; }
        const float inv = 1.f / ssum;
        #pragma unroll
        for (int j = 0; j < 16; ++j) s_w[base + j] = e[j] * inv;
    }
    __syncthreads();

    // phase 1: tap precompute — 1024 samples, 4 per thread
    #pragma unroll
    for (int i = 0; i < 4; ++i) {
        const int s = t + i * 256;
        const int q = s >> 7, r = s & 127;
        const int h = r >> 4, lp = r & 15, l = lp >> 2;
        const int gq = bq0 + q;             // < M_PAD: qo is padded
        const float2 off = __half22float2(*(const __half2*)&qo[(size_t)gq * 384 + r * 2]);
        const float rx = s_ref[q * 8 + l * 2];
        const float ry = s_ref[q * 8 + l * 2 + 1];
        const int W = c_W[l], H = c_H[l], st = c_ST[l];
        const float fW = (float)W, fH = (float)H;
        const float lx = (rx + off.x / fW) * fW - 0.5f;
        const float ly = (ry + off.y / fH) * fH - 0.5f;
        const float x0f = floorf(lx), y0f = floorf(ly);
        const float fx = lx - x0f, fy = ly - y0f;
        const int x0 = (int)x0f, y0 = (int)y0f;
        const float aw = s_w[s];
        const float wx[2] = {1.f - fx, fx};
        const float wy[2] = {1.f - fy, fy};
        #pragma unroll
        for (int dy = 0; dy < 2; ++dy) {
            #pragma unroll
            for (int dx = 0; dx < 2; ++dx) {
                const int xi = x0 + dx, yi = y0 + dy;
                const bool ok = (xi >= 0) & (xi < W) & (yi >= 0) & (yi < H);
                const unsigned int idx = ok ? (unsigned int)(st + yi * W + xi) : 0u;
                const float w = ok ? aw * wy[dy] * wx[dx] : 0.f;
                const unsigned int pw = (unsigned int)f2hu(w);
                s_tap[q * 8 + h][lp * 4 + dy * 2 + dx] = idx | (pw << 16);
            }
        }
    }
    __syncthreads();

    // phase 2: gather + pk_fma_f16 weighted sum. 32 lanes/query: h 0..7, c8 0..3.
    const int q   = t >> 5;
    const int l32 = t & 31;
    const int h   = l32 >> 2;
    const int c8  = l32 & 3;
    const int gq  = bq0 + q;
    const int b   = (gq >= nq) ? 1 : 0;
    const __half* __restrict__ vb = vproj + (size_t)b * nv * EMBED + h * 32 + c8 * 8;
    const uint4* __restrict__ tapq = (const uint4*)s_tap[q * 8 + h];

    __align__(16) __half2 acc2[4];
    #pragma unroll
    for (int i = 0; i < 4; ++i) acc2[i] = __float2half2_rn(0.f);

    #pragma unroll 2
    for (int g = 0; g < 16; ++g) {
        const uint4 tq = tapq[g];
        const int4 r0 = *(const int4*)(vb + (size_t)(tq.x & 0xFFFFu) * EMBED);
        const int4 r1 = *(const int4*)(vb + (size_t)(tq.y & 0xFFFFu) * EMBED);
        const int4 r2 = *(const int4*)(vb + (size_t)(tq.z & 0xFFFFu) * EMBED);
        const int4 r3 = *(const int4*)(vb + (size_t)(tq.w & 0xFFFFu) * EMBED);
        const __half2 w0 = __half2half2(__ushort_as_half((unsigned short)(tq.x >> 16)));
        const __half2 w1 = __half2half2(__ushort_as_half((unsigned short)(tq.y >> 16)));
        const __half2 w2 = __half2half2(__ushort_as_half((unsigned short)(tq.z >> 16)));
        const __half2 w3 = __half2half2(__ushort_as_half((unsigned short)(tq.w >> 16)));
        const __half2* h0 = (const __half2*)&r0;
        const __half2* h1 = (const __half2*)&r1;
        const __half2* h2 = (const __half2*)&r2;
        const __half2* h3 = (const __half2*)&r3;
        #pragma unroll
        for (int i = 0; i < 4; ++i) {
            acc2[i] = __hfma2(w0, h0[i], acc2[i]);
            acc2[i] = __hfma2(w1, h1[i], acc2[i]);
            acc2[i] = __hfma2(w2, h2[i], acc2[i]);
            acc2[i] = __hfma2(w3, h3[i], acc2[i]);
        }
    }

    if (gq < M)
        *(int4*)&core[(size_t)gq * 256 + h * 32 + c8 * 8] = *(const int4*)acc2;
}

// ---------------- launch ----------------
extern "C" void kernel_launch(void* const* d_in, const int* in_sizes, int n_in,
                              void* d_out, int out_size, void* d_ws, size_t ws_size,
                              hipStream_t stream) {
    const float* query  = (const float*)d_in[0];
    const float* refp   = (const float*)d_in[1];
    const float* value  = (const float*)d_in[2];
    const float* W_samp = (const float*)d_in[6];
    const float* b_samp = (const float*)d_in[7];
    const float* W_attn = (const float*)d_in[8];
    const float* b_attn = (const float*)d_in[9];
    const float* W_val  = (const float*)d_in[10];
    const float* b_val  = (const float*)d_in[11];
    const float* W_out  = (const float*)d_in[12];
    const float* b_out  = (const float*)d_in[13];
    float* out = (float*)d_out;

    const int M  = in_sizes[0] / EMBED;   // 26588
    const int nq = NV_PER_B;
    const int nv = NV_PER_B;
    const int Mp = M_PAD;

    // workspace carve-up (~75.4 MB)
    char* p = (char*)d_ws;
    __half* coreh  = (__half*)p; p += (size_t)Mp * 256 * 2;
    __half* vproj  = (__half*)p; p += (size_t)Mp * 256 * 2;
    __half* qo     = (__half*)p; p += (size_t)Mp * 384 * 2;
    __half* q_h    = (__half*)p; p += (size_t)Mp * 256 * 2;
    __half* v_h    = (__half*)p; p += (size_t)Mp * 256 * 2;
    __half* wv_h   = (__half*)p; p += 65536 * 2;
    __half* wcat_h = (__half*)p; p += 98304 * 2;
    __half* wo_h   = (__half*)p; p += 65536 * 2;
    float*  biascat= (float*)p;  p += 384 * 4;

    const int n_real4 = M * 256 / 4;
    const int n_pad4  = Mp * 256 / 4;
    dim3 blk(256);

    convert_kernel<<<dim3((n_pad4 + 255) / 256), blk, 0, stream>>>(
        query, value, W_val, W_samp, W_attn, W_out, b_samp, b_attn,
        q_h, v_h, wv_h, wcat_h, wo_h, biascat, n_real4, n_pad4);

    const int mb = Mp / 128;  // 208
    proj_gemm_kernel<<<dim3(mb, 5), blk, 0, stream>>>(
        v_h, wv_h, b_val, vproj, q_h, wcat_h, biascat, qo);

    msda_core_kernel<<<dim3((M + NQPB - 1) / NQPB), blk, 0, stream>>>(
        vproj, refp, qo, coreh, nq, nv, M);

    gemm_out_kernel<<<dim3(mb, 2), blk, 0, stream>>>(
        coreh, wo_h, b_out, out, M);
}